// Round 15
// baseline (761.967 us; speedup 1.0000x reference)
//
#include <hip/hip_runtime.h>
#include <hip/hip_bf16.h>
#include <hip/hip_fp16.h>

#define B_ 32
#define T_ 64
#define S_ 400
#define SPAD_ 512
#define H_ 512
#define E_ 1024
#define EMB_ 256
#define V_ 32000
#define NCB_ 500          // V / 64 partial col-blocks

#define KEYS_BLOCKS 200   // 50 row-tiles(256) x 4 col-tiles(128)
#define CVT_BLOCKS 48
#define MEGA_BLOCKS (8 + KEYS_BLOCKS + CVT_BLOCKS)
#define MEGA_LDS (65536 + 33280 + 4096 + 32)
#define CTX_LDS (102400 + 2048)

typedef _Float16 f16;
typedef _Float16 half8 __attribute__((ext_vector_type(8)));
typedef float f32x4 __attribute__((ext_vector_type(4)));
typedef float f32x16 __attribute__((ext_vector_type(16)));
typedef unsigned uint4v __attribute__((ext_vector_type(4)));

__device__ __forceinline__ void gl_lds16(const void* g, void* l) {
  __builtin_amdgcn_global_load_lds(
      (const __attribute__((address_space(1))) void*)g,
      (__attribute__((address_space(3))) void*)l, 16, 0, 0);
}

__device__ __forceinline__ float sigmoidf_(float x) { return 1.f / (1.f + expf(-x)); }

// IF$-coherent (L1+L2 bypass) accesses for cross-XCD producer/consumer.
__device__ __forceinline__ uint4v load_b128_sys(const void* p) {
  uint4v r;
  asm volatile("global_load_dwordx4 %0, %1, off sc0 sc1" : "=v"(r) : "v"(p) : "memory");
  return r;
}
__device__ __forceinline__ void store_b128_sys(void* p, uint4v v) {
  asm volatile("global_store_dwordx4 %0, %1, off sc0 sc1" :: "v"(p), "v"(v) : "memory");
}

// ---------------- prep+xpart merged kernel ----------------
// Blocks 0..255: xpart GEMM tile (128x128): xpart[r][c] = x[r,:]·W_ih[perm(c),:] + bias
//   where x[r=t*B+b,:] = emb[target[b][t]], perm(c) = (c&3)*512 + (c>>2)  (gate-interleave).
// Blocks 256..319: prep-lite grid-stride: Wperm, hbuf slot0 + poison, W_attn cvt.
__global__ __launch_bounds__(256) void prep_xpart_kernel(
    const int* __restrict__ target, const float* __restrict__ emb,
    const float* __restrict__ Wih, const float* __restrict__ b_ih,
    const float* __restrict__ b_hh, float* __restrict__ xpart,
    const float* __restrict__ Whh, f16* __restrict__ Wperm,
    const float* __restrict__ h0, f16* __restrict__ hbuf,
    const float* __restrict__ Wattn, f16* __restrict__ Wattn_f) {
  const int blk = blockIdx.x, tid = threadIdx.x;
  if (blk < 256) {
    __shared__ __align__(16) char As[128 * 64];
    __shared__ __align__(16) char Bs[128 * 64];
    const int lane = tid & 63, wave = tid >> 6;
    const int wr = (wave >> 1) * 64, wc = (wave & 1) * 64;
    const int fr = lane & 15, fq = lane >> 4;
    const int row0 = (blk & 15) * 128, col0 = (blk >> 4) * 128;

    f32x4 acc[4][4];
#pragma unroll
    for (int i = 0; i < 4; ++i)
#pragma unroll
      for (int j = 0; j < 4; ++j) acc[i][j] = {0.f, 0.f, 0.f, 0.f};

    for (int k0 = 0; k0 < EMB_; k0 += 32) {
      __syncthreads();
#pragma unroll
      for (int it = 0; it < 2; ++it) {
        int idx = tid + it * 256;
        int r = idx >> 2, cq = idx & 3;
        int t = (row0 + r) >> 5, b = (row0 + r) & 31;
        int tok = target[b * T_ + t];
        const float* ap = emb + (size_t)tok * EMB_ + k0 + cq * 8;
        float4 a0 = *reinterpret_cast<const float4*>(ap);
        float4 a1 = *reinterpret_cast<const float4*>(ap + 4);
        union { f16 h[8]; unsigned long long u[2]; } pa;
#pragma unroll
        for (int q = 0; q < 4; ++q) { pa.h[q] = (f16)((const float*)&a0)[q]; pa.h[4 + q] = (f16)((const float*)&a1)[q]; }
        *reinterpret_cast<unsigned long long*>(As + r * 64 + cq * 16) = pa.u[0];
        *reinterpret_cast<unsigned long long*>(As + r * 64 + cq * 16 + 8) = pa.u[1];
        int c = col0 + r;
        int orig = (c & 3) * 512 + (c >> 2);
        const float* bp = Wih + (size_t)orig * EMB_ + k0 + cq * 8;
        float4 b0 = *reinterpret_cast<const float4*>(bp);
        float4 b1 = *reinterpret_cast<const float4*>(bp + 4);
        union { f16 h[8]; unsigned long long u[2]; } pb;
#pragma unroll
        for (int q = 0; q < 4; ++q) { pb.h[q] = (f16)((const float*)&b0)[q]; pb.h[4 + q] = (f16)((const float*)&b1)[q]; }
        *reinterpret_cast<unsigned long long*>(Bs + r * 64 + cq * 16) = pb.u[0];
        *reinterpret_cast<unsigned long long*>(Bs + r * 64 + cq * 16 + 8) = pb.u[1];
      }
      __syncthreads();
      half8 af[4], bfr[4];
#pragma unroll
      for (int mi = 0; mi < 4; ++mi)
        af[mi] = *reinterpret_cast<const half8*>(As + (wr + mi * 16 + fr) * 64 + fq * 16);
#pragma unroll
      for (int ni = 0; ni < 4; ++ni)
        bfr[ni] = *reinterpret_cast<const half8*>(Bs + (wc + ni * 16 + fr) * 64 + fq * 16);
#pragma unroll
      for (int mi = 0; mi < 4; ++mi)
#pragma unroll
        for (int ni = 0; ni < 4; ++ni)
          acc[mi][ni] = __builtin_amdgcn_mfma_f32_16x16x32_f16(af[mi], bfr[ni], acc[mi][ni], 0, 0, 0);
    }
#pragma unroll
    for (int mi = 0; mi < 4; ++mi)
#pragma unroll
      for (int ni = 0; ni < 4; ++ni) {
        int col = col0 + wc + ni * 16 + fr;
        int orig = (col & 3) * 512 + (col >> 2);
        float bias = b_ih[orig] + b_hh[orig];
#pragma unroll
        for (int r = 0; r < 4; ++r) {
          int row = row0 + wr + mi * 16 + fq * 4 + r;
          xpart[(size_t)row * 2048 + col] = acc[mi][ni][r] + bias;
        }
      }
  } else {
    const int base = (blk - 256) * 256 + tid;
    const int stride = 64 * 256;
    for (int idx = base; idx < H_ * H_; idx += stride) {   // Wperm
      int j = idx >> 9, k = idx & 511;
#pragma unroll
      for (int gg = 0; gg < 4; ++gg)
        Wperm[((size_t)(j * 4 + gg)) * H_ + k] = (f16)Whh[((size_t)(gg * H_ + j)) * H_ + k];
    }
    for (int idx = base; idx < H_ * E_ / 2; idx += stride) {   // W_attn cvt
      float2 v = reinterpret_cast<const float2*>(Wattn)[idx];
      union { f16 h[2]; unsigned u; } o;
      o.h[0] = (f16)v.x; o.h[1] = (f16)v.y;
      reinterpret_cast<unsigned*>(Wattn_f)[idx] = o.u;
    }
    for (int idx = base; idx < T_ * B_ * H_ / 8; idx += stride) {  // poison slots 1..64
      uint4v p = {0xFFFFFFFFu, 0xFFFFFFFFu, 0xFFFFFFFFu, 0xFFFFFFFFu};
      reinterpret_cast<uint4v*>(reinterpret_cast<char*>(hbuf) + (size_t)B_ * H_ * 2)[idx] = p;
    }
    for (int idx = base; idx < B_ * H_; idx += stride)   // slot 0
      hbuf[idx] = (f16)h0[idx];
  }
}

// ---------------- generic MFMA GEMM (cat + fallback paths) ----------------
template <int OUTK, bool DO_TANH>
__global__ __launch_bounds__(256) void gemm_bt_kernel(const f16* __restrict__ A,
                                                      const f16* __restrict__ W,
                                                      const float* __restrict__ bias,
                                                      void* __restrict__ outp,
                                                      int M, int N, int K) {
  __shared__ __align__(16) char As[128 * 64];
  __shared__ __align__(16) char Bs[128 * 64];
  const int tid = threadIdx.x;
  const int lane = tid & 63, wave = tid >> 6;
  const int wr = (wave >> 1) * 64, wc = (wave & 1) * 64;
  const int fr = lane & 15, fq = lane >> 4;
  const int row0 = blockIdx.x * 128, col0 = blockIdx.y * 128;

  f32x4 acc[4][4];
#pragma unroll
  for (int i = 0; i < 4; ++i)
#pragma unroll
    for (int j = 0; j < 4; ++j) acc[i][j] = {0.f, 0.f, 0.f, 0.f};

  for (int k0 = 0; k0 < K; k0 += 32) {
    __syncthreads();
#pragma unroll
    for (int i = 0; i < 2; ++i) {
      int o = tid * 16 + i * 4096;
      int r = o >> 6, kk = (o & 63) >> 1;
      gl_lds16(A + (size_t)(row0 + r) * K + (k0 + kk), As + o);
      gl_lds16(W + (size_t)(col0 + r) * K + (k0 + kk), Bs + o);
    }
    __syncthreads();
    half8 af[4], bfr[4];
#pragma unroll
    for (int mi = 0; mi < 4; ++mi)
      af[mi] = *reinterpret_cast<const half8*>(As + (wr + mi * 16 + fr) * 64 + fq * 16);
#pragma unroll
    for (int ni = 0; ni < 4; ++ni)
      bfr[ni] = *reinterpret_cast<const half8*>(Bs + (wc + ni * 16 + fr) * 64 + fq * 16);
#pragma unroll
    for (int mi = 0; mi < 4; ++mi)
#pragma unroll
      for (int ni = 0; ni < 4; ++ni)
        acc[mi][ni] = __builtin_amdgcn_mfma_f32_16x16x32_f16(af[mi], bfr[ni], acc[mi][ni], 0, 0, 0);
  }

#pragma unroll
  for (int mi = 0; mi < 4; ++mi)
#pragma unroll
    for (int ni = 0; ni < 4; ++ni)
#pragma unroll
      for (int r = 0; r < 4; ++r) {
        int row = row0 + wr + mi * 16 + fq * 4 + r;
        int col = col0 + wc + ni * 16 + fr;
        float v = acc[mi][ni][r] + bias[col];
        if (DO_TANH) v = tanhf(v);
        if (OUTK == 0) {
          ((float*)outp)[(size_t)row * N + col] = v;
        } else if (OUTK == 1) {
          ((f16*)outp)[(size_t)row * N + col] = (f16)v;
        } else {
          int orow = (row & 31) * T_ + (row >> 5);
          ((float*)outp)[(size_t)orow * N + col] = v;
        }
      }
}

// ---------------- MEGA kernel: lstm (blocks 0-7) + keys GEMM (8..207) + cvt (208..255) ----
__global__ __launch_bounds__(512, 1) void mega_kernel(
    const float* __restrict__ xpart, const f16* __restrict__ Wperm,
    const float* __restrict__ c0, f16* __restrict__ hbuf,
    const float* __restrict__ enc, const f16* __restrict__ Wattn_f,
    const float* __restrict__ b_attn, f16* __restrict__ keys,
    const float* __restrict__ wc_src, f16* __restrict__ wc_dst,
    const float* __restrict__ wo_src, f16* __restrict__ wo_dst) {
  extern __shared__ char lds[];
  const int blk = blockIdx.x, tid = threadIdx.x;
  const int lane = tid & 63, wave = tid >> 6;

  if (blk < 8) {
    // ================= LSTM (measured-best R4 structure) =================
    char* Abuf = lds;                                      // 2 x 32768
    float* gates = (float*)(lds + 65536);                  // [32][260]
    unsigned* hstage = (unsigned*)(lds + 65536 + 33280);   // 4 KB
    int* flags = (int*)(lds + 65536 + 33280 + 4096);       // 8 ints
    const int g = blk;
    const int ln31 = lane & 31, lh = lane >> 5;

    if (tid < 8) flags[tid] = 0;

    half8 wf[32];
    {
      const f16* wrow = Wperm + ((size_t)(g * 256 + wave * 32 + ln31)) * H_ + lh * 8;
#pragma unroll
      for (int kc = 0; kc < 32; ++kc)
        wf[kc] = *reinterpret_cast<const half8*>(wrow + kc * 16);
    }

    const int b = tid >> 4, qd = tid & 15;
    float cst[4];
#pragma unroll
    for (int jj = 0; jj < 4; ++jj)
      cst[jj] = c0[b * H_ + g * 64 + qd * 4 + jj];

    __syncthreads();

    for (int t = 0; t < T_; ++t) {
      const float* xr = xpart + ((size_t)(t * B_ + b)) * (4 * H_) + g * 256 + qd * 16;
      float4 xv[4];
#pragma unroll
      for (int i = 0; i < 4; ++i) xv[i] = *reinterpret_cast<const float4*>(xr + i * 4);

      {
        int p = (t == 0) ? wave : (wave + (wave >= g ? 1 : 0));
        bool duty = (t == 0) ? true : (wave < 7);
        if (duty) {
          const char* sb = (const char*)hbuf + (size_t)t * 32768 + ln31 * 1024 + p * 128 + lh * 16;
          while (true) {
            uint4v v0 = load_b128_sys(sb);
            uint4v v1 = load_b128_sys(sb + 32);
            uint4v v2 = load_b128_sys(sb + 64);
            uint4v v3 = load_b128_sys(sb + 96);
            asm volatile("s_waitcnt vmcnt(0)" ::: "memory");
            __builtin_amdgcn_sched_barrier(0);
            unsigned bad = 0;
#pragma unroll
            for (int d = 0; d < 4; ++d)
              bad |= (unsigned)(v0[d] == 0xFFFFFFFFu) | (unsigned)(v1[d] == 0xFFFFFFFFu) |
                     (unsigned)(v2[d] == 0xFFFFFFFFu) | (unsigned)(v3[d] == 0xFFFFFFFFu);
            if (__all(bad == 0)) {
              char* ab = Abuf + (size_t)(t & 1) * 32768 + lane * 16;
              *(uint4v*)(ab + (size_t)(4 * p + 0) * 1024) = v0;
              *(uint4v*)(ab + (size_t)(4 * p + 1) * 1024) = v1;
              *(uint4v*)(ab + (size_t)(4 * p + 2) * 1024) = v2;
              *(uint4v*)(ab + (size_t)(4 * p + 3) * 1024) = v3;
              asm volatile("s_waitcnt lgkmcnt(0)" ::: "memory");
              __builtin_amdgcn_sched_barrier(0);
              if (lane == 0)
                __hip_atomic_fetch_add(&flags[p], 1, __ATOMIC_RELAXED,
                                       __HIP_MEMORY_SCOPE_WORKGROUP);
              break;
            }
          }
        }
      }

      f32x16 acc;
#pragma unroll
      for (int r = 0; r < 16; ++r) acc[r] = 0.f;
      const char* abR = Abuf + (size_t)(t & 1) * 32768 + lane * 16;
      const char* hsR = (const char*)hstage + lane * 16;
      const int thr = t + 1;
#pragma unroll
      for (int ps = 0; ps < 8; ++ps) {
        if (ps == g && t > 0) {
#pragma unroll
          for (int c = 0; c < 4; ++c) {
            half8 a = *(const half8*)(hsR + c * 1024);
            acc = __builtin_amdgcn_mfma_f32_32x32x16_f16(a, wf[4 * ps + c], acc, 0, 0, 0);
          }
        } else {
          while (__hip_atomic_load(&flags[ps], __ATOMIC_ACQUIRE,
                                   __HIP_MEMORY_SCOPE_WORKGROUP) < thr) {}
#pragma unroll
          for (int c = 0; c < 4; ++c) {
            half8 a = *(const half8*)(abR + (size_t)(4 * ps + c) * 1024);
            acc = __builtin_amdgcn_mfma_f32_32x32x16_f16(a, wf[4 * ps + c], acc, 0, 0, 0);
          }
        }
      }
#pragma unroll
      for (int r = 0; r < 16; ++r) {
        int row = (r & 3) + 8 * (r >> 2) + 4 * lh;
        gates[row * 260 + wave * 32 + ln31] = acc[r];
      }
      __syncthreads();

      const float* gr = &gates[b * 260 + qd * 16];
      float hv[4];
#pragma unroll
      for (int jj = 0; jj < 4; ++jj) {
        float gi = gr[jj * 4 + 0] + xv[jj].x;
        float gf = gr[jj * 4 + 1] + xv[jj].y;
        float gg = gr[jj * 4 + 2] + xv[jj].z;
        float go = gr[jj * 4 + 3] + xv[jj].w;
        cst[jj] = sigmoidf_(gf) * cst[jj] + sigmoidf_(gi) * tanhf(gg);
        hv[jj] = sigmoidf_(go) * tanhf(cst[jj]);
      }
      union { f16 h[2]; unsigned u; } pk0, pk1;
      pk0.h[0] = (f16)hv[0]; pk0.h[1] = (f16)hv[1];
      pk1.h[0] = (f16)hv[2]; pk1.h[1] = (f16)hv[3];
      {
        int cp0 = 2 * qd, cp1 = 2 * qd + 1;
        hstage[((cp0 >> 3) * 64 + ((cp0 >> 2) & 1) * 32 + b) * 4 + (cp0 & 3)] = pk0.u;
        hstage[((cp1 >> 3) * 64 + ((cp1 >> 2) & 1) * 32 + b) * 4 + (cp1 & 3)] = pk1.u;
      }
      __syncthreads();

      if (tid < 256) {
        int kcl = tid >> 6, l2 = tid & 63;
        uint4v v = *(const uint4v*)((const char*)hstage + (kcl * 64 + l2) * 16);
        store_b128_sys((char*)hbuf + (size_t)(t + 1) * 32768 + (l2 & 31) * 1024 +
                           g * 128 + kcl * 32 + (l2 >> 5) * 16,
                       v);
      }
    }
  } else if (blk < 8 + KEYS_BLOCKS) {
    // ================= keys GEMM =================
    char* As = lds;              // 256 x 32 f16 = 16 KB
    char* Bs = lds + 16384;      // 128 x 32 f16 = 8 KB
    const int kid = blk - 8;
    const int row0 = (kid % 50) * 256, col0 = (kid / 50) * 128;
    const int wr = (wave >> 1) * 64, wc = (wave & 1) * 64;
    const int fr = lane & 15, fq = lane >> 4;

    f32x4 acc[4][4];
#pragma unroll
    for (int i = 0; i < 4; ++i)
#pragma unroll
      for (int j = 0; j < 4; ++j) acc[i][j] = {0.f, 0.f, 0.f, 0.f};

    for (int k0 = 0; k0 < E_; k0 += 32) {
      __syncthreads();
      float4 av[4];
#pragma unroll
      for (int i = 0; i < 4; ++i) {
        int idx = tid + i * 512;
        int r = idx >> 3, ck = (idx & 7) * 4;
        av[i] = *reinterpret_cast<const float4*>(enc + (size_t)(row0 + r) * E_ + k0 + ck);
      }
      {
        int o = tid * 16;
        int r = o >> 6, kk = (o & 63) >> 1;
        gl_lds16(Wattn_f + (size_t)(col0 + r) * E_ + (k0 + kk), Bs + o);
      }
#pragma unroll
      for (int i = 0; i < 4; ++i) {
        int idx = tid + i * 512;
        int r = idx >> 3, ck = (idx & 7) * 4;
        union { f16 h[4]; unsigned long long u; } p;
        p.h[0] = (f16)av[i].x; p.h[1] = (f16)av[i].y;
        p.h[2] = (f16)av[i].z; p.h[3] = (f16)av[i].w;
        *reinterpret_cast<unsigned long long*>(As + r * 64 + ck * 2) = p.u;
      }
      __syncthreads();
      half8 af[4], bf[4];
#pragma unroll
      for (int mi = 0; mi < 4; ++mi)
        af[mi] = *reinterpret_cast<const half8*>(As + (wr + mi * 16 + fr) * 64 + fq * 16);
#pragma unroll
      for (int ni = 0; ni < 4; ++ni)
        bf[ni] = *reinterpret_cast<const half8*>(Bs + (wc + ni * 16 + fr) * 64 + fq * 16);
#pragma unroll
      for (int mi = 0; mi < 4; ++mi)
#pragma unroll
        for (int ni = 0; ni < 4; ++ni)
          acc[mi][ni] = __builtin_amdgcn_mfma_f32_16x16x32_f16(af[mi], bf[ni], acc[mi][ni], 0, 0, 0);
    }
#pragma unroll
    for (int mi = 0; mi < 4; ++mi)
#pragma unroll
      for (int ni = 0; ni < 4; ++ni)
#pragma unroll
        for (int r = 0; r < 4; ++r) {
          int row = row0 + wr + mi * 16 + fq * 4 + r;
          int col = col0 + wc + ni * 16 + fr;
          keys[(size_t)row * H_ + col] = (f16)(acc[mi][ni][r] + b_attn[col]);
        }
  } else {
    // ================= cvt: W_cat then W_out =================
    const int N2WC = H_ * (E_ + H_) / 2, N2WO = V_ * H_ / 2;
    const int total = N2WC + N2WO;
    const int stride = CVT_BLOCKS * 512;
    for (int i = (blk - 8 - KEYS_BLOCKS) * 512 + tid; i < total; i += stride) {
      const float* s; f16* d; int j;
      if (i < N2WC) { s = wc_src; d = wc_dst; j = i; }
      else { s = wo_src; d = wo_dst; j = i - N2WC; }
      float2 v = reinterpret_cast<const float2*>(s)[j];
      union { f16 h[2]; unsigned u; } o;
      o.h[0] = (f16)v.x; o.h[1] = (f16)v.y;
      reinterpret_cast<unsigned*>(d)[j] = o.u;
    }
  }
}

// ---------------- scores via MFMA (raw, unnormalized) ----------------
__global__ __launch_bounds__(256) void scores_mfma_kernel(const f16* __restrict__ keys,
                                                          const f16* __restrict__ hseq,
                                                          float* __restrict__ attnw) {
  const int b = blockIdx.y;
  const int lane = threadIdx.x & 63, wave = threadIdx.x >> 6;
  const int ln31 = lane & 31, lh = lane >> 5;
  const int stile = blockIdx.x * 128 + wave * 32;
  const f16* ar  = keys + ((size_t)(stile + ln31) * B_ + b) * H_ + lh * 8;
  const f16* br0 = hseq + ((size_t)ln31 * B_ + b) * H_ + lh * 8;
  const f16* br1 = hseq + ((size_t)(ln31 + 32) * B_ + b) * H_ + lh * 8;
  f32x16 ac0, ac1;
#pragma unroll
  for (int r = 0; r < 16; ++r) { ac0[r] = 0.f; ac1[r] = 0.f; }
#pragma unroll
  for (int kc = 0; kc < 32; ++kc) {
    half8 a  = *reinterpret_cast<const half8*>(ar + kc * 16);
    half8 h0 = *reinterpret_cast<const half8*>(br0 + kc * 16);
    half8 h1 = *reinterpret_cast<const half8*>(br1 + kc * 16);
    ac0 = __builtin_amdgcn_mfma_f32_32x32x16_f16(a, h0, ac0, 0, 0, 0);
    ac1 = __builtin_amdgcn_mfma_f32_32x32x16_f16(a, h1, ac1, 0, 0, 0);
  }
#pragma unroll
  for (int r = 0; r < 16; ++r) {
    int s = stile + (r & 3) + 8 * (r >> 2) + 4 * lh;
    if (s < S_) {
      attnw[((size_t)b * S_ + s) * T_ + ln31]      = ac0[r];
      attnw[((size_t)b * S_ + s) * T_ + 32 + ln31] = ac1[r];
    }
  }
}

// ---------------- ctx + softmax + catcopy: grid (B, 17) ----------------
// y<16: load raw scores (400x64) into LDS, mask+softmax in LDS, ctx e-chunk.
// y==16: h copy into catin[:, E:E+H).
__global__ __launch_bounds__(256) void ctx_cat_kernel(const float* __restrict__ attnw,
                                                      const int* __restrict__ mask,
                                                      const float* __restrict__ enc,
                                                      const f16* __restrict__ hseq,
                                                      f16* __restrict__ catin) {
  int b = blockIdx.x, y = blockIdx.y;
  if (y == 16) {
    for (int i = threadIdx.x; i < 64 * 64; i += 256) {
      int t = i >> 6, c = i & 63;
      uint4v v = *(const uint4v*)((const char*)hseq + ((size_t)t * B_ + b) * 1024 + c * 16);
      *(uint4v*)((char*)catin + ((size_t)t * B_ + b) * 3072 + 2048 + c * 16) = v;
    }
    return;
  }
  extern __shared__ char clds[];
  float* sc = (float*)clds;                 // [400][64] = 100 KB
  float* red = (float*)(clds + 102400);     // [2][64][4]

  // softmax in LDS: thread (t = tid&63, q = tid>>6) owns s in [q*100, q*100+100)
  const int t = threadIdx.x & 63, q = threadIdx.x >> 6;
  float m = -3.4e38f;
  for (int i = 0; i < 100; ++i) {
    int s = q * 100 + i;
    float v = attnw[((size_t)b * S_ + s) * T_ + t];
    if (mask[b * S_ + s] == 0) v = -1e18f;
    sc[s * 64 + t] = v;
    m = fmaxf(m, v);
  }
  red[(0 * 64 + t) * 4 + q] = m;
  __syncthreads();
  float mt = fmaxf(fmaxf(red[(0 * 64 + t) * 4 + 0], red[(0 * 64 + t) * 4 + 1]),
                   fmaxf(red[(0 * 64 + t) * 4 + 2], red[(0 * 64 + t) * 4 + 3]));
  float sum = 0.f;
  for (int i = 0; i < 100; ++i) {
    int s = q * 100 + i;
    float e = expf(sc[s * 64 + t] - mt);
    sc[s * 64 + t] = e;
    sum += e;
  }
  red[(1 * 64 + t) * 4 + q] = sum;
  __syncthreads();
  float den = red[(1 * 64 + t) * 4 + 0] + red[(1 * 64 + t) * 4 + 1] +
              red[(1 * 64 + t) * 4 + 2] + red[(1 * 64 + t) * 4 + 3];
  float inv = 1.f / den;
  for (int i = 0; i < 100; ++i) sc[(q * 100 + i) * 64 + t] *= inv;
  __syncthreads();

  // ctx accumulation (probs from LDS, broadcast reads)
  int e0 = y * 64;
  int el = threadIdx.x & 63, tq = threadIdx.x >> 6;
  float acc[16];
#pragma unroll
  for (int i = 0; i < 16; ++i) acc[i] = 0.f;
  for (int s = 0; s < S_; ++s) {
    float v = enc[((size_t)s * B_ + b) * E_ + e0 + el];
#pragma unroll
    for (int i = 0; i < 16; ++i) acc[i] += sc[s * 64 + tq * 16 + i] * v;
  }
#pragma unroll
  for (int i = 0; i < 16; ++i) {
    int tt = tq * 16 + i;
    catin[((size_t)tt * B_ + b) * (E_ + H_) + e0 + el] = (f16)acc[i];
  }
}

// ---------------- out GEMM 256x128 + XCD-chunked remap ----------------
__global__ __launch_bounds__(512) void gemm_out256_kernel(const f16* __restrict__ A,
                                                          const f16* __restrict__ W,
                                                          const float* __restrict__ bias,
                                                          f16* __restrict__ lbuf,
                                                          float* __restrict__ pm,
                                                          float* __restrict__ ps) {
  __shared__ __align__(16) char As[256 * 64];   // 16 KB
  __shared__ __align__(16) char Bs[128 * 64];   // 8 KB
  const int tid = threadIdx.x;
  const int lane = tid & 63, wave = tid >> 6;
  const int wr = (wave >> 1) * 64, wc = (wave & 1) * 64;
  const int fr = lane & 15, fq = lane >> 4;
  const int k = blockIdx.x + blockIdx.y * 8;        // gridDim.x == 8
  const int p = (k % 8) * 250 + k / 8;              // bijective on [0,2000)
  const int row0 = (p % 8) * 256, col0 = (p / 8) * 128;

  f32x4 acc[4][4];
#pragma unroll
  for (int i = 0; i < 4; ++i)
#pragma unroll
    for (int j = 0; j < 4; ++j) acc[i][j] = {0.f, 0.f, 0.f, 0.f};

  for (int k0 = 0; k0 < H_; k0 += 32) {
    __syncthreads();
    {
      int o = tid * 16;
      int r = o >> 6, kk = (o & 63) >> 1;
      gl_lds16(A + (size_t)(row0 + r) * H_ + (k0 + kk), As + o);
      gl_lds16(W + (size_t)(col0 + r) * H_ + (k0 + kk), Bs + o);
      o += 8192; r = o >> 6; kk = (o & 63) >> 1;
      gl_lds16(A + (size_t)(row0 + r) * H_ + (k0 + kk), As + o);
    }
    __syncthreads();
    half8 af[4], bfr[4];
#pragma unroll
    for (int mi = 0; mi < 4; ++mi)
      af[mi] = *reinterpret_cast<const half8*>(As + (wr + mi * 16 + fr) * 64 + fq * 16);
#pragma unroll
    for (int ni = 0; ni < 4; ++ni)
      bfr[ni] = *reinterpret_cast<const half8*>(Bs + (wc + ni * 16 + fr) * 64 + fq * 16);
#pragma unroll
    for (int mi = 0; mi < 4; ++mi)
#pragma unroll
      for (int ni = 0; ni < 4; ++ni)
        acc[mi][ni] = __builtin_amdgcn_mfma_f32_16x16x32_f16(af[mi], bfr[ni], acc[mi][ni], 0, 0, 0);
  }

#pragma unroll
  for (int mi = 0; mi < 4; ++mi)
#pragma unroll
    for (int r = 0; r < 4; ++r) {
      int row = row0 + wr + mi * 16 + fq * 4 + r;
      float v0 = acc[mi][0][r] + bias[col0 + wc + fr];
      float v1 = acc[mi][1][r] + bias[col0 + wc + 16 + fr];
      float v2 = acc[mi][2][r] + bias[col0 + wc + 32 + fr];
      float v3 = acc[mi][3][r] + bias[col0 + wc + 48 + fr];
      f16* lp = lbuf + (size_t)row * V_ + col0 + wc + fr;
      lp[0] = (f16)v0; lp[16] = (f16)v1; lp[32] = (f16)v2; lp[48] = (f16)v3;
      float mx = fmaxf(fmaxf(v0, v1), fmaxf(v2, v3));
#pragma unroll
      for (int d2 = 1; d2 <= 8; d2 <<= 1) mx = fmaxf(mx, __shfl_xor(mx, d2));
      float sm = expf(v0 - mx) + expf(v1 - mx) + expf(v2 - mx) + expf(v3 - mx);
#pragma unroll
      for (int d2 = 1; d2 <= 8; d2 <<= 1) sm += __shfl_xor(sm, d2);
      if (fr == 0) {
        int cb = (col0 + wc) >> 6;
        pm[(size_t)row * NCB_ + cb] = mx;
        ps[(size_t)row * NCB_ + cb] = sm;
      }
    }
}

// ---------------- final: lse (inline combine) + out[b][t][v] = (f32)lbuf - lse ----------
__global__ __launch_bounds__(256) void final_out_kernel(const f16* __restrict__ lbuf,
                                                        const float* __restrict__ pm,
                                                        const float* __restrict__ ps,
                                                        float* __restrict__ out) {
  int j = blockIdx.x;                  // out row = b*T + t
  int b = j >> 6, t = j & 63;
  int r = t * B_ + b;
  int tid = threadIdx.x;
  __shared__ float red[4];
  __shared__ float lsh;

  float mv0 = -3.4e38f, sv0 = 0.f, mv1 = -3.4e38f, sv1 = 0.f;
  if (tid < NCB_) { mv0 = pm[(size_t)r * NCB_ + tid]; sv0 = ps[(size_t)r * NCB_ + tid]; }
  int i2 = tid + 256;
  if (i2 < NCB_) { mv1 = pm[(size_t)r * NCB_ + i2]; sv1 = ps[(size_t)r * NCB_ + i2]; }
  float m = fmaxf(mv0, mv1);
#pragma unroll
  for (int o = 32; o > 0; o >>= 1) m = fmaxf(m, __shfl_xor(m, o));
  if ((tid & 63) == 0) red[tid >> 6] = m;
  __syncthreads();
  float mm = fmaxf(fmaxf(red[0], red[1]), fmaxf(red[2], red[3]));
  float s = sv0 * expf(mv0 - mm) + sv1 * expf(mv1 - mm);
#pragma unroll
  for (int o = 32; o > 0; o >>= 1) s += __shfl_xor(s, o);
  __syncthreads();
  if ((tid & 63) == 0) red[tid >> 6] = s;
  __syncthreads();
  if (tid == 0) lsh = mm + logf(red[0] + red[1] + red[2] + red[3]);
  __syncthreads();
  float l = lsh;

  const half8* src = reinterpret_cast<const half8*>(lbuf + (size_t)r * V_);
  float4* dst = reinterpret_cast<float4*>(out + (size_t)j * V_);
  for (int c = tid; c < V_ / 8; c += 256) {
    half8 h = src[c];
    float4 o1, o2;
    o1.x = (float)h[0] - l; o1.y = (float)h[1] - l;
    o1.z = (float)h[2] - l; o1.w = (float)h[3] - l;
    o2.x = (float)h[4] - l; o2.y = (float)h[5] - l;
    o2.z = (float)h[6] - l; o2.w = (float)h[7] - l;
    dst[c * 2] = o1; dst[c * 2 + 1] = o2;
  }
}

// ---------------- fallback single-pass log-softmax (f32 in d_out) ----------------
__global__ __launch_bounds__(512, 1) void logsm_kernel(float* __restrict__ out) {
  int r = blockIdx.x;
  size_t base = (size_t)r * V_;
  int tid = threadIdx.x;
  float4* op = reinterpret_cast<float4*>(out + base);
  float4 v[16];
  float m = -3.4e38f;
#pragma unroll
  for (int k = 0; k < 16; ++k) {
    int c = tid + (k << 9);
    if (c < 8000) {
      v[k] = op[c];
      m = fmaxf(m, fmaxf(fmaxf(v[k].x, v[k].y), fmaxf(v[k].z, v[k].w)));
    }
  }
  __shared__ float red[8];
#pragma unroll
  for (int o = 32; o > 0; o >>= 1) m = fmaxf(m, __shfl_xor(m, o));
  if ((tid & 63) == 0) red[tid >> 6] = m;
  __syncthreads();
  float mm = red[0];
#pragma unroll
  for (int i = 1; i < 8; ++i) mm = fmaxf(mm, red[i]);
  float s = 0.f;
#pragma unroll
  for (int k = 0; k < 16; ++k) {
    int c = tid + (k << 9);
    if (c < 8000)
      s += expf(v[k].x - mm) + expf(v[k].y - mm) + expf(v[k].z - mm) + expf(v[k].w - mm);
  }
#pragma unroll
  for (int o = 32; o > 0; o >>= 1) s += __shfl_xor(s, o);
  __syncthreads();
  if ((tid & 63) == 0) red[tid >> 6] = s;
  __syncthreads();
  s = 0.f;
#pragma unroll
  for (int i = 0; i < 8; ++i) s += red[i];
  float lse = mm + logf(s);
#pragma unroll
  for (int k = 0; k < 16; ++k) {
    int c = tid + (k << 9);
    if (c < 8000) {
      float4 o4;
      o4.x = v[k].x - lse; o4.y = v[k].y - lse;
      o4.z = v[k].z - lse; o4.w = v[k].w - lse;
      op[c] = o4;
    }
  }
}

extern "C" void kernel_launch(void* const* d_in, const int* in_sizes, int n_in,
                              void* d_out, int out_size, void* d_ws, size_t ws_size,
                              hipStream_t stream) {
  const int*   target = (const int*)d_in[0];
  const float* h0     = (const float*)d_in[1];
  const float* c0     = (const float*)d_in[2];
  const float* enc    = (const float*)d_in[3];
  const int*   mask   = (const int*)d_in[4];
  const float* emb    = (const float*)d_in[5];
  const float* W_ih   = (const float*)d_in[6];
  const float* b_ih   = (const float*)d_in[7];
  const float* W_hh   = (const float*)d_in[8];
  const float* b_hh   = (const float*)d_in[9];
  const float* W_attn = (const float*)d_in[10];
  const float* b_attn = (const float*)d_in[11];
  const float* W_cat  = (const float*)d_in[12];
  const float* b_cat  = (const float*)d_in[13];
  const float* W_out  = (const float*)d_in[14];
  const float* b_out  = (const float*)d_in[15];

  char* ws = (char*)d_ws;
  size_t off = 0;
  auto alloc = [&](size_t bytes) {
    void* p = ws + off;
    off = (off + bytes + 255) & ~(size_t)255;
    return p;
  };
  f16*   keys_f   = (f16*)alloc((size_t)SPAD_ * B_ * H_ * 2);
  f16*   Wattn_f  = (f16*)alloc((size_t)H_ * E_ * 2);
  f16*   Wcat_f   = (f16*)alloc((size_t)H_ * (E_ + H_) * 2);
  f16*   Wout_f   = (f16*)alloc((size_t)V_ * H_ * 2);
  f16*   Wperm    = (f16*)alloc((size_t)4 * H_ * H_ * 2);
  float* xpart    = (float*)alloc((size_t)T_ * B_ * 4 * H_ * 4);
  f16*   catin_f  = (f16*)alloc((size_t)T_ * B_ * (E_ + H_) * 2);
  float* attnw    = (float*)alloc((size_t)B_ * S_ * T_ * 4);
  f16*   catbuf_f = (f16*)alloc((size_t)T_ * B_ * H_ * 2);
  f16*   hbuf     = (f16*)alloc((size_t)(T_ + 1) * B_ * H_ * 2);   // 65 slots

  size_t extra = ((size_t)T_ * B_ * V_ * 2 + 255 + (size_t)T_ * B_ * NCB_ * 4 * 2 + 512);
  bool pathA = (off + extra) <= ws_size;
  f16* lbuf = nullptr; float* pm = nullptr; float* psb = nullptr;
  if (pathA) {
    lbuf = (f16*)alloc((size_t)T_ * B_ * V_ * 2);
    pm   = (float*)alloc((size_t)T_ * B_ * NCB_ * 4);
    psb  = (float*)alloc((size_t)T_ * B_ * NCB_ * 4);
  }
  (void)in_sizes; (void)n_in; (void)out_size;

  f16* hseq_f = hbuf + (size_t)B_ * H_;   // slots 1..64 ARE hseq

  // prep-lite + xpart GEMM fused
  prep_xpart_kernel<<<320, 256, 0, stream>>>(target, emb, W_ih, b_ih, b_hh, xpart,
                                             W_hh, Wperm, h0, hbuf, W_attn, Wattn_f);

  // mega: lstm + keys GEMM + W_cat/W_out cvt, all co-resident
  mega_kernel<<<MEGA_BLOCKS, 512, MEGA_LDS, stream>>>(
      xpart, Wperm, c0, hbuf, enc, Wattn_f, b_attn, keys_f,
      W_cat, Wcat_f, W_out, Wout_f);

  scores_mfma_kernel<<<dim3(SPAD_ / 128, B_), 256, 0, stream>>>(keys_f, hseq_f, attnw);
  // ctx + in-LDS softmax + h-copy (softmax kernel folded in)
  ctx_cat_kernel<<<dim3(B_, 17), 256, CTX_LDS, stream>>>(attnw, mask, enc, hseq_f, catin_f);

  // cat: [T*B, H] = tanh(catin @ W_cat^T + b_cat)   (f16 out)
  gemm_bt_kernel<1, true><<<dim3((T_ * B_) / 128, H_ / 128), 256, 0, stream>>>(
      catin_f, Wcat_f, b_cat, catbuf_f, T_ * B_, H_, E_ + H_);

  if (pathA) {
    gemm_out256_kernel<<<dim3(8, 250), 512, 0, stream>>>(
        catbuf_f, Wout_f, b_out, lbuf, pm, psb);
    final_out_kernel<<<T_ * B_, 256, 0, stream>>>(lbuf, pm, psb, (float*)d_out);
  } else {
    gemm_bt_kernel<2, false><<<dim3((T_ * B_) / 128, V_ / 128), 256, 0, stream>>>(
        catbuf_f, Wout_f, b_out, (float*)d_out, T_ * B_, V_, H_);
    logsm_kernel<<<B_ * T_, 512, 0, stream>>>((float*)d_out);
  }
}

// Round 16
// 717.456 us; speedup vs baseline: 1.0620x; 1.0620x over previous
//
#include <hip/hip_runtime.h>
#include <hip/hip_bf16.h>
#include <hip/hip_fp16.h>

#define B_ 32
#define T_ 64
#define S_ 400
#define SPAD_ 512
#define H_ 512
#define E_ 1024
#define EMB_ 256
#define V_ 32000
#define NCB_ 500          // V / 64 partial col-blocks

#define KEYS_BLOCKS 200   // 50 row-tiles(256) x 4 col-tiles(128)
#define CVT_BLOCKS 48
#define MEGA_BLOCKS (8 + KEYS_BLOCKS + CVT_BLOCKS)
#define MEGA_LDS (65536 + 33280 + 4096 + 32)

typedef _Float16 f16;
typedef _Float16 half8 __attribute__((ext_vector_type(8)));
typedef float f32x4 __attribute__((ext_vector_type(4)));
typedef float f32x16 __attribute__((ext_vector_type(16)));
typedef unsigned uint4v __attribute__((ext_vector_type(4)));

__device__ __forceinline__ void gl_lds16(const void* g, void* l) {
  __builtin_amdgcn_global_load_lds(
      (const __attribute__((address_space(1))) void*)g,
      (__attribute__((address_space(3))) void*)l, 16, 0, 0);
}

__device__ __forceinline__ float sigmoidf_(float x) { return 1.f / (1.f + expf(-x)); }

// IF$-coherent (L1+L2 bypass) accesses for cross-XCD producer/consumer.
__device__ __forceinline__ uint4v load_b128_sys(const void* p) {
  uint4v r;
  asm volatile("global_load_dwordx4 %0, %1, off sc0 sc1" : "=v"(r) : "v"(p) : "memory");
  return r;
}
__device__ __forceinline__ void store_b128_sys(void* p, uint4v v) {
  asm volatile("global_store_dwordx4 %0, %1, off sc0 sc1" :: "v"(p), "v"(v) : "memory");
}

// ---------------- prep: permuted weights/bias, h slot0, poison, W_attn cvt, x gather ----
// Row permutation: new row jg = j*4+g  <->  old row g*H+j   (j in [0,512), g in [0,4))
__global__ __launch_bounds__(256) void prep_kernel(const float* __restrict__ b_ih,
                                                   const float* __restrict__ b_hh,
                                                   float* __restrict__ biasperm,
                                                   const float* __restrict__ Whh,
                                                   f16* __restrict__ Wperm,
                                                   const float* __restrict__ Wih,
                                                   f16* __restrict__ Wihp,
                                                   const float* __restrict__ h0,
                                                   f16* __restrict__ hbuf,
                                                   const float* __restrict__ Wattn,
                                                   f16* __restrict__ Wattn_f,
                                                   const int* __restrict__ target,
                                                   const float* __restrict__ emb,
                                                   f16* __restrict__ xin) {
  int idx = blockIdx.x * 256 + threadIdx.x;   // grid covers H_*H_ = 262144
  if (idx < 4 * H_) {
    int j = idx >> 2, gg = idx & 3;
    biasperm[idx] = b_ih[gg * H_ + j] + b_hh[gg * H_ + j];
  }
  if (idx < B_ * H_) hbuf[idx] = (f16)h0[idx];   // slot 0
  if (idx < T_ * B_ * H_ / 8) {                  // poison slots 1..64 (131072 x 16B)
    uint4v p = {0xFFFFFFFFu, 0xFFFFFFFFu, 0xFFFFFFFFu, 0xFFFFFFFFu};
    reinterpret_cast<uint4v*>(reinterpret_cast<char*>(hbuf) + (size_t)B_ * H_ * 2)[idx] = p;
  }
  {
    int j = idx >> 9, k = idx & 511;          // W_hh: [2048][512]
#pragma unroll
    for (int gg = 0; gg < 4; ++gg)
      Wperm[((size_t)(j * 4 + gg)) * H_ + k] = (f16)Whh[((size_t)(gg * H_ + j)) * H_ + k];
  }
  if (idx < H_ * EMB_) {                       // W_ih: [2048][256]
    int j = idx >> 8, k = idx & 255;
#pragma unroll
    for (int gg = 0; gg < 4; ++gg)
      Wihp[((size_t)(j * 4 + gg)) * EMB_ + k] = (f16)Wih[((size_t)(gg * H_ + j)) * EMB_ + k];
  }
  {                                            // W_attn cvt: H*E/2 = 262144 float2 chunks
    float2 v = reinterpret_cast<const float2*>(Wattn)[idx];
    union { f16 h[2]; unsigned u; } o;
    o.h[0] = (f16)v.x; o.h[1] = (f16)v.y;
    reinterpret_cast<unsigned*>(Wattn_f)[idx] = o.u;
  }
  {                                            // embedding gather: 2 cols per idx
    int rr = idx >> 7, cc = (idx & 127) * 2;   // rr = t*B + b
    int t = rr >> 5, bb = rr & 31;
    int tok = target[bb * T_ + t];
    float2 ev = *reinterpret_cast<const float2*>(emb + (size_t)tok * EMB_ + cc);
    union { f16 h[2]; unsigned u; } o2;
    o2.h[0] = (f16)ev.x; o2.h[1] = (f16)ev.y;
    *reinterpret_cast<unsigned*>(xin + (size_t)rr * EMB_ + cc) = o2.u;
  }
}

// ---------------- generic MFMA GEMM (xpart + cat + fallback paths) ----------------
template <int OUTK, bool DO_TANH>
__global__ __launch_bounds__(256) void gemm_bt_kernel(const f16* __restrict__ A,
                                                      const f16* __restrict__ W,
                                                      const float* __restrict__ bias,
                                                      void* __restrict__ outp,
                                                      int M, int N, int K) {
  __shared__ __align__(16) char As[128 * 64];
  __shared__ __align__(16) char Bs[128 * 64];
  const int tid = threadIdx.x;
  const int lane = tid & 63, wave = tid >> 6;
  const int wr = (wave >> 1) * 64, wc = (wave & 1) * 64;
  const int fr = lane & 15, fq = lane >> 4;
  const int row0 = blockIdx.x * 128, col0 = blockIdx.y * 128;

  f32x4 acc[4][4];
#pragma unroll
  for (int i = 0; i < 4; ++i)
#pragma unroll
    for (int j = 0; j < 4; ++j) acc[i][j] = {0.f, 0.f, 0.f, 0.f};

  for (int k0 = 0; k0 < K; k0 += 32) {
    __syncthreads();
#pragma unroll
    for (int i = 0; i < 2; ++i) {
      int o = tid * 16 + i * 4096;
      int r = o >> 6, kk = (o & 63) >> 1;
      gl_lds16(A + (size_t)(row0 + r) * K + (k0 + kk), As + o);
      gl_lds16(W + (size_t)(col0 + r) * K + (k0 + kk), Bs + o);
    }
    __syncthreads();
    half8 af[4], bfr[4];
#pragma unroll
    for (int mi = 0; mi < 4; ++mi)
      af[mi] = *reinterpret_cast<const half8*>(As + (wr + mi * 16 + fr) * 64 + fq * 16);
#pragma unroll
    for (int ni = 0; ni < 4; ++ni)
      bfr[ni] = *reinterpret_cast<const half8*>(Bs + (wc + ni * 16 + fr) * 64 + fq * 16);
#pragma unroll
    for (int mi = 0; mi < 4; ++mi)
#pragma unroll
      for (int ni = 0; ni < 4; ++ni)
        acc[mi][ni] = __builtin_amdgcn_mfma_f32_16x16x32_f16(af[mi], bfr[ni], acc[mi][ni], 0, 0, 0);
  }

#pragma unroll
  for (int mi = 0; mi < 4; ++mi)
#pragma unroll
    for (int ni = 0; ni < 4; ++ni)
#pragma unroll
      for (int r = 0; r < 4; ++r) {
        int row = row0 + wr + mi * 16 + fq * 4 + r;
        int col = col0 + wc + ni * 16 + fr;
        float v = acc[mi][ni][r] + bias[col];
        if (DO_TANH) v = tanhf(v);
        if (OUTK == 0) {
          ((float*)outp)[(size_t)row * N + col] = v;
        } else if (OUTK == 1) {
          ((f16*)outp)[(size_t)row * N + col] = (f16)v;
        } else {
          int orow = (row & 31) * T_ + (row >> 5);
          ((float*)outp)[(size_t)orow * N + col] = v;
        }
      }
}

// ---------------- MEGA kernel: lstm (blocks 0-7) + keys GEMM (8..207) + cvt (208..255) ----
// All 256 blocks co-resident (1/CU). Non-lstm blocks have no dependency on lstm.
__global__ __launch_bounds__(512, 1) void mega_kernel(
    const float* __restrict__ xpart, const f16* __restrict__ Wperm,
    const float* __restrict__ c0, f16* __restrict__ hbuf,
    const float* __restrict__ enc, const f16* __restrict__ Wattn_f,
    const float* __restrict__ b_attn, f16* __restrict__ keys,
    const float* __restrict__ wc_src, f16* __restrict__ wc_dst,
    const float* __restrict__ wo_src, f16* __restrict__ wo_dst) {
  extern __shared__ char lds[];
  const int blk = blockIdx.x, tid = threadIdx.x;
  const int lane = tid & 63, wave = tid >> 6;

  if (blk < 8) {
    // ================= LSTM (measured-best R4 structure) =================
    char* Abuf = lds;                                      // 2 x 32768
    float* gates = (float*)(lds + 65536);                  // [32][260]
    unsigned* hstage = (unsigned*)(lds + 65536 + 33280);   // 4 KB
    int* flags = (int*)(lds + 65536 + 33280 + 4096);       // 8 ints
    const int g = blk;
    const int ln31 = lane & 31, lh = lane >> 5;

    if (tid < 8) flags[tid] = 0;

    half8 wf[32];
    {
      const f16* wrow = Wperm + ((size_t)(g * 256 + wave * 32 + ln31)) * H_ + lh * 8;
#pragma unroll
      for (int kc = 0; kc < 32; ++kc)
        wf[kc] = *reinterpret_cast<const half8*>(wrow + kc * 16);
    }

    const int b = tid >> 4, qd = tid & 15;
    float cst[4];
#pragma unroll
    for (int jj = 0; jj < 4; ++jj)
      cst[jj] = c0[b * H_ + g * 64 + qd * 4 + jj];

    __syncthreads();

    for (int t = 0; t < T_; ++t) {
      const float* xr = xpart + ((size_t)(t * B_ + b)) * (4 * H_) + g * 256 + qd * 16;
      float4 xv[4];
#pragma unroll
      for (int i = 0; i < 4; ++i) xv[i] = *reinterpret_cast<const float4*>(xr + i * 4);

      {
        int p = (t == 0) ? wave : (wave + (wave >= g ? 1 : 0));
        bool duty = (t == 0) ? true : (wave < 7);
        if (duty) {
          const char* sb = (const char*)hbuf + (size_t)t * 32768 + ln31 * 1024 + p * 128 + lh * 16;
          while (true) {
            uint4v v0 = load_b128_sys(sb);
            uint4v v1 = load_b128_sys(sb + 32);
            uint4v v2 = load_b128_sys(sb + 64);
            uint4v v3 = load_b128_sys(sb + 96);
            asm volatile("s_waitcnt vmcnt(0)" ::: "memory");
            __builtin_amdgcn_sched_barrier(0);
            unsigned bad = 0;
#pragma unroll
            for (int d = 0; d < 4; ++d)
              bad |= (unsigned)(v0[d] == 0xFFFFFFFFu) | (unsigned)(v1[d] == 0xFFFFFFFFu) |
                     (unsigned)(v2[d] == 0xFFFFFFFFu) | (unsigned)(v3[d] == 0xFFFFFFFFu);
            if (__all(bad == 0)) {
              char* ab = Abuf + (size_t)(t & 1) * 32768 + lane * 16;
              *(uint4v*)(ab + (size_t)(4 * p + 0) * 1024) = v0;
              *(uint4v*)(ab + (size_t)(4 * p + 1) * 1024) = v1;
              *(uint4v*)(ab + (size_t)(4 * p + 2) * 1024) = v2;
              *(uint4v*)(ab + (size_t)(4 * p + 3) * 1024) = v3;
              asm volatile("s_waitcnt lgkmcnt(0)" ::: "memory");
              __builtin_amdgcn_sched_barrier(0);
              if (lane == 0)
                __hip_atomic_fetch_add(&flags[p], 1, __ATOMIC_RELAXED,
                                       __HIP_MEMORY_SCOPE_WORKGROUP);
              break;
            }
          }
        }
      }

      f32x16 acc;
#pragma unroll
      for (int r = 0; r < 16; ++r) acc[r] = 0.f;
      const char* abR = Abuf + (size_t)(t & 1) * 32768 + lane * 16;
      const char* hsR = (const char*)hstage + lane * 16;
      const int thr = t + 1;
#pragma unroll
      for (int ps = 0; ps < 8; ++ps) {
        if (ps == g && t > 0) {
#pragma unroll
          for (int c = 0; c < 4; ++c) {
            half8 a = *(const half8*)(hsR + c * 1024);
            acc = __builtin_amdgcn_mfma_f32_32x32x16_f16(a, wf[4 * ps + c], acc, 0, 0, 0);
          }
        } else {
          while (__hip_atomic_load(&flags[ps], __ATOMIC_ACQUIRE,
                                   __HIP_MEMORY_SCOPE_WORKGROUP) < thr) {}
#pragma unroll
          for (int c = 0; c < 4; ++c) {
            half8 a = *(const half8*)(abR + (size_t)(4 * ps + c) * 1024);
            acc = __builtin_amdgcn_mfma_f32_32x32x16_f16(a, wf[4 * ps + c], acc, 0, 0, 0);
          }
        }
      }
#pragma unroll
      for (int r = 0; r < 16; ++r) {
        int row = (r & 3) + 8 * (r >> 2) + 4 * lh;
        gates[row * 260 + wave * 32 + ln31] = acc[r];
      }
      __syncthreads();

      const float* gr = &gates[b * 260 + qd * 16];
      float hv[4];
#pragma unroll
      for (int jj = 0; jj < 4; ++jj) {
        float gi = gr[jj * 4 + 0] + xv[jj].x;
        float gf = gr[jj * 4 + 1] + xv[jj].y;
        float gg = gr[jj * 4 + 2] + xv[jj].z;
        float go = gr[jj * 4 + 3] + xv[jj].w;
        cst[jj] = sigmoidf_(gf) * cst[jj] + sigmoidf_(gi) * tanhf(gg);
        hv[jj] = sigmoidf_(go) * tanhf(cst[jj]);
      }
      union { f16 h[2]; unsigned u; } pk0, pk1;
      pk0.h[0] = (f16)hv[0]; pk0.h[1] = (f16)hv[1];
      pk1.h[0] = (f16)hv[2]; pk1.h[1] = (f16)hv[3];
      {
        int cp0 = 2 * qd, cp1 = 2 * qd + 1;
        hstage[((cp0 >> 3) * 64 + ((cp0 >> 2) & 1) * 32 + b) * 4 + (cp0 & 3)] = pk0.u;
        hstage[((cp1 >> 3) * 64 + ((cp1 >> 2) & 1) * 32 + b) * 4 + (cp1 & 3)] = pk1.u;
      }
      __syncthreads();

      if (tid < 256) {
        int kcl = tid >> 6, l2 = tid & 63;
        uint4v v = *(const uint4v*)((const char*)hstage + (kcl * 64 + l2) * 16);
        store_b128_sys((char*)hbuf + (size_t)(t + 1) * 32768 + (l2 & 31) * 1024 +
                           g * 128 + kcl * 32 + (l2 >> 5) * 16,
                       v);
      }
    }
  } else if (blk < 8 + KEYS_BLOCKS) {
    // ================= keys GEMM: keys[row][col] = enc_f32[row,:]·Wattn[col,:] + b ====
    char* As = lds;              // 256 x 32 f16 = 16 KB
    char* Bs = lds + 16384;      // 128 x 32 f16 = 8 KB
    const int kid = blk - 8;
    const int row0 = (kid % 50) * 256, col0 = (kid / 50) * 128;
    const int wr = (wave >> 1) * 64, wc = (wave & 1) * 64;
    const int fr = lane & 15, fq = lane >> 4;

    f32x4 acc[4][4];
#pragma unroll
    for (int i = 0; i < 4; ++i)
#pragma unroll
      for (int j = 0; j < 4; ++j) acc[i][j] = {0.f, 0.f, 0.f, 0.f};

    for (int k0 = 0; k0 < E_; k0 += 32) {
      __syncthreads();
      float4 av[4];
#pragma unroll
      for (int i = 0; i < 4; ++i) {
        int idx = tid + i * 512;            // 0..2047 float4 chunks
        int r = idx >> 3, ck = (idx & 7) * 4;
        av[i] = *reinterpret_cast<const float4*>(enc + (size_t)(row0 + r) * E_ + k0 + ck);
      }
      {
        int o = tid * 16;                   // 512 x 16B = 8 KB
        int r = o >> 6, kk = (o & 63) >> 1;
        gl_lds16(Wattn_f + (size_t)(col0 + r) * E_ + (k0 + kk), Bs + o);
      }
#pragma unroll
      for (int i = 0; i < 4; ++i) {
        int idx = tid + i * 512;
        int r = idx >> 3, ck = (idx & 7) * 4;
        union { f16 h[4]; unsigned long long u; } p;
        p.h[0] = (f16)av[i].x; p.h[1] = (f16)av[i].y;
        p.h[2] = (f16)av[i].z; p.h[3] = (f16)av[i].w;
        *reinterpret_cast<unsigned long long*>(As + r * 64 + ck * 2) = p.u;
      }
      __syncthreads();
      half8 af[4], bf[4];
#pragma unroll
      for (int mi = 0; mi < 4; ++mi)
        af[mi] = *reinterpret_cast<const half8*>(As + (wr + mi * 16 + fr) * 64 + fq * 16);
#pragma unroll
      for (int ni = 0; ni < 4; ++ni)
        bf[ni] = *reinterpret_cast<const half8*>(Bs + (wc + ni * 16 + fr) * 64 + fq * 16);
#pragma unroll
      for (int mi = 0; mi < 4; ++mi)
#pragma unroll
        for (int ni = 0; ni < 4; ++ni)
          acc[mi][ni] = __builtin_amdgcn_mfma_f32_16x16x32_f16(af[mi], bf[ni], acc[mi][ni], 0, 0, 0);
    }
#pragma unroll
    for (int mi = 0; mi < 4; ++mi)
#pragma unroll
      for (int ni = 0; ni < 4; ++ni)
#pragma unroll
        for (int r = 0; r < 4; ++r) {
          int row = row0 + wr + mi * 16 + fq * 4 + r;
          int col = col0 + wc + ni * 16 + fr;
          keys[(size_t)row * H_ + col] = (f16)(acc[mi][ni][r] + b_attn[col]);
        }
  } else {
    // ================= cvt: W_cat then W_out, grid-stride float2 chunks =================
    const int N2WC = H_ * (E_ + H_) / 2, N2WO = V_ * H_ / 2;
    const int total = N2WC + N2WO;
    const int stride = CVT_BLOCKS * 512;
    for (int i = (blk - 8 - KEYS_BLOCKS) * 512 + tid; i < total; i += stride) {
      const float* s; f16* d; int j;
      if (i < N2WC) { s = wc_src; d = wc_dst; j = i; }
      else { s = wo_src; d = wo_dst; j = i - N2WC; }
      float2 v = reinterpret_cast<const float2*>(s)[j];
      union { f16 h[2]; unsigned u; } o;
      o.h[0] = (f16)v.x; o.h[1] = (f16)v.y;
      reinterpret_cast<unsigned*>(d)[j] = o.u;
    }
  }
}

// ---------------- scores via MFMA ----------------
__global__ __launch_bounds__(256) void scores_mfma_kernel(const f16* __restrict__ keys,
                                                          const f16* __restrict__ hseq,
                                                          float* __restrict__ attnw) {
  const int b = blockIdx.y;
  const int lane = threadIdx.x & 63, wave = threadIdx.x >> 6;
  const int ln31 = lane & 31, lh = lane >> 5;
  const int stile = blockIdx.x * 128 + wave * 32;
  const f16* ar  = keys + ((size_t)(stile + ln31) * B_ + b) * H_ + lh * 8;
  const f16* br0 = hseq + ((size_t)ln31 * B_ + b) * H_ + lh * 8;
  const f16* br1 = hseq + ((size_t)(ln31 + 32) * B_ + b) * H_ + lh * 8;
  f32x16 ac0, ac1;
#pragma unroll
  for (int r = 0; r < 16; ++r) { ac0[r] = 0.f; ac1[r] = 0.f; }
#pragma unroll
  for (int kc = 0; kc < 32; ++kc) {
    half8 a  = *reinterpret_cast<const half8*>(ar + kc * 16);
    half8 h0 = *reinterpret_cast<const half8*>(br0 + kc * 16);
    half8 h1 = *reinterpret_cast<const half8*>(br1 + kc * 16);
    ac0 = __builtin_amdgcn_mfma_f32_32x32x16_f16(a, h0, ac0, 0, 0, 0);
    ac1 = __builtin_amdgcn_mfma_f32_32x32x16_f16(a, h1, ac1, 0, 0, 0);
  }
#pragma unroll
  for (int r = 0; r < 16; ++r) {
    int s = stile + (r & 3) + 8 * (r >> 2) + 4 * lh;
    if (s < S_) {
      attnw[((size_t)b * S_ + s) * T_ + ln31]      = ac0[r];
      attnw[((size_t)b * S_ + s) * T_ + 32 + ln31] = ac1[r];
    }
  }
}

// ---------------- masked softmax over s for each (b,t), in place ----------------
__global__ __launch_bounds__(64) void softmax_kernel(float* __restrict__ attnw,
                                                     const int* __restrict__ mask) {
  int b = blockIdx.x, t = blockIdx.y, l = threadIdx.x;
  float vals[7];
  float m = -3.4e38f;
#pragma unroll
  for (int i = 0; i < 7; ++i) {
    int s = l + i * 64;
    float v = -3.4e38f;
    if (s < S_) {
      v = attnw[((size_t)b * S_ + s) * T_ + t];
      if (mask[b * S_ + s] == 0) v = -1e18f;
    }
    vals[i] = v;
    m = fmaxf(m, v);
  }
#pragma unroll
  for (int o = 32; o > 0; o >>= 1) m = fmaxf(m, __shfl_xor(m, o));
  float sum = 0.f;
#pragma unroll
  for (int i = 0; i < 7; ++i) {
    int s = l + i * 64;
    if (s < S_) { float e = expf(vals[i] - m); vals[i] = e; sum += e; }
  }
#pragma unroll
  for (int o = 32; o > 0; o >>= 1) sum += __shfl_xor(sum, o);
  float inv = 1.f / sum;
#pragma unroll
  for (int i = 0; i < 7; ++i) {
    int s = l + i * 64;
    if (s < S_) attnw[((size_t)b * S_ + s) * T_ + t] = vals[i] * inv;
  }
}

// ---------------- ctx + catcopy: grid (B, 17); y<16: ctx e-chunk, y==16: h copy ----------
__global__ __launch_bounds__(256) void ctx_cat_kernel(const float* __restrict__ attnw,
                                                      const float* __restrict__ enc,
                                                      const f16* __restrict__ hseq,
                                                      f16* __restrict__ catin) {
  int b = blockIdx.x, y = blockIdx.y;
  if (y == 16) {
    for (int i = threadIdx.x; i < 64 * 64; i += 256) {
      int t = i >> 6, c = i & 63;
      uint4v v = *(const uint4v*)((const char*)hseq + ((size_t)t * B_ + b) * 1024 + c * 16);
      *(uint4v*)((char*)catin + ((size_t)t * B_ + b) * 3072 + 2048 + c * 16) = v;
    }
    return;
  }
  int e0 = y * 64;
  int el = threadIdx.x & 63, tq = threadIdx.x >> 6;
  __shared__ float a_lds[100 * 64];
  float acc[16];
#pragma unroll
  for (int i = 0; i < 16; ++i) acc[i] = 0.f;
  for (int scn = 0; scn < 4; ++scn) {
    __syncthreads();
    for (int i = threadIdx.x; i < 6400; i += 256)
      a_lds[i] = attnw[((size_t)b * S_ + scn * 100) * T_ + i];
    __syncthreads();
    for (int sl = 0; sl < 100; ++sl) {
      int s = scn * 100 + sl;
      float v = enc[((size_t)s * B_ + b) * E_ + e0 + el];
#pragma unroll
      for (int i = 0; i < 16; ++i) acc[i] += a_lds[sl * 64 + tq * 16 + i] * v;
    }
  }
#pragma unroll
  for (int i = 0; i < 16; ++i) {
    int t = tq * 16 + i;
    catin[((size_t)t * B_ + b) * (E_ + H_) + e0 + el] = (f16)acc[i];
  }
}

// ---------------- out GEMM 256x128: f16 logits + per-(row,64col) partials ----------------
__global__ __launch_bounds__(512) void gemm_out256_kernel(const f16* __restrict__ A,
                                                          const f16* __restrict__ W,
                                                          const float* __restrict__ bias,
                                                          f16* __restrict__ lbuf,
                                                          float* __restrict__ pm,
                                                          float* __restrict__ ps) {
  __shared__ __align__(16) char As[256 * 64];   // 16 KB
  __shared__ __align__(16) char Bs[128 * 64];   // 8 KB
  const int tid = threadIdx.x;
  const int lane = tid & 63, wave = tid >> 6;
  const int wr = (wave >> 1) * 64, wc = (wave & 1) * 64;
  const int fr = lane & 15, fq = lane >> 4;
  const int row0 = blockIdx.x * 256, col0 = blockIdx.y * 128;

  f32x4 acc[4][4];
#pragma unroll
  for (int i = 0; i < 4; ++i)
#pragma unroll
    for (int j = 0; j < 4; ++j) acc[i][j] = {0.f, 0.f, 0.f, 0.f};

  for (int k0 = 0; k0 < H_; k0 += 32) {
    __syncthreads();
    {
      int o = tid * 16;
      int r = o >> 6, kk = (o & 63) >> 1;
      gl_lds16(A + (size_t)(row0 + r) * H_ + (k0 + kk), As + o);
      gl_lds16(W + (size_t)(col0 + r) * H_ + (k0 + kk), Bs + o);
      o += 8192; r = o >> 6; kk = (o & 63) >> 1;
      gl_lds16(A + (size_t)(row0 + r) * H_ + (k0 + kk), As + o);
    }
    __syncthreads();
    half8 af[4], bfr[4];
#pragma unroll
    for (int mi = 0; mi < 4; ++mi)
      af[mi] = *reinterpret_cast<const half8*>(As + (wr + mi * 16 + fr) * 64 + fq * 16);
#pragma unroll
    for (int ni = 0; ni < 4; ++ni)
      bfr[ni] = *reinterpret_cast<const half8*>(Bs + (wc + ni * 16 + fr) * 64 + fq * 16);
#pragma unroll
    for (int mi = 0; mi < 4; ++mi)
#pragma unroll
      for (int ni = 0; ni < 4; ++ni)
        acc[mi][ni] = __builtin_amdgcn_mfma_f32_16x16x32_f16(af[mi], bfr[ni], acc[mi][ni], 0, 0, 0);
  }

#pragma unroll
  for (int mi = 0; mi < 4; ++mi)
#pragma unroll
    for (int r = 0; r < 4; ++r) {
      int row = row0 + wr + mi * 16 + fq * 4 + r;
      float v0 = acc[mi][0][r] + bias[col0 + wc + fr];
      float v1 = acc[mi][1][r] + bias[col0 + wc + 16 + fr];
      float v2 = acc[mi][2][r] + bias[col0 + wc + 32 + fr];
      float v3 = acc[mi][3][r] + bias[col0 + wc + 48 + fr];
      f16* lp = lbuf + (size_t)row * V_ + col0 + wc + fr;
      lp[0] = (f16)v0; lp[16] = (f16)v1; lp[32] = (f16)v2; lp[48] = (f16)v3;
      float mx = fmaxf(fmaxf(v0, v1), fmaxf(v2, v3));
#pragma unroll
      for (int d2 = 1; d2 <= 8; d2 <<= 1) mx = fmaxf(mx, __shfl_xor(mx, d2));
      float sm = expf(v0 - mx) + expf(v1 - mx) + expf(v2 - mx) + expf(v3 - mx);
#pragma unroll
      for (int d2 = 1; d2 <= 8; d2 <<= 1) sm += __shfl_xor(sm, d2);
      if (fr == 0) {
        int cb = (col0 + wc) >> 6;
        pm[(size_t)row * NCB_ + cb] = mx;
        ps[(size_t)row * NCB_ + cb] = sm;
      }
    }
}

// ---------------- final: lse (inline combine) + out[b][t][v] = (f32)lbuf - lse ----------
__global__ __launch_bounds__(256) void final_out_kernel(const f16* __restrict__ lbuf,
                                                        const float* __restrict__ pm,
                                                        const float* __restrict__ ps,
                                                        float* __restrict__ out) {
  int j = blockIdx.x;                  // out row = b*T + t
  int b = j >> 6, t = j & 63;
  int r = t * B_ + b;
  int tid = threadIdx.x;
  __shared__ float red[4];
  __shared__ float lsh;

  // inline lse: 500 partials, 2 per thread
  float mv0 = -3.4e38f, sv0 = 0.f, mv1 = -3.4e38f, sv1 = 0.f;
  if (tid < NCB_) { mv0 = pm[(size_t)r * NCB_ + tid]; sv0 = ps[(size_t)r * NCB_ + tid]; }
  int i2 = tid + 256;
  if (i2 < NCB_) { mv1 = pm[(size_t)r * NCB_ + i2]; sv1 = ps[(size_t)r * NCB_ + i2]; }
  float m = fmaxf(mv0, mv1);
#pragma unroll
  for (int o = 32; o > 0; o >>= 1) m = fmaxf(m, __shfl_xor(m, o));
  if ((tid & 63) == 0) red[tid >> 6] = m;
  __syncthreads();
  float mm = fmaxf(fmaxf(red[0], red[1]), fmaxf(red[2], red[3]));
  float s = sv0 * expf(mv0 - mm) + sv1 * expf(mv1 - mm);
#pragma unroll
  for (int o = 32; o > 0; o >>= 1) s += __shfl_xor(s, o);
  __syncthreads();
  if ((tid & 63) == 0) red[tid >> 6] = s;
  __syncthreads();
  if (tid == 0) lsh = mm + logf(red[0] + red[1] + red[2] + red[3]);
  __syncthreads();
  float l = lsh;

  const half8* src = reinterpret_cast<const half8*>(lbuf + (size_t)r * V_);
  float4* dst = reinterpret_cast<float4*>(out + (size_t)j * V_);
  for (int c = tid; c < V_ / 8; c += 256) {
    half8 h = src[c];
    float4 o1, o2;
    o1.x = (float)h[0] - l; o1.y = (float)h[1] - l;
    o1.z = (float)h[2] - l; o1.w = (float)h[3] - l;
    o2.x = (float)h[4] - l; o2.y = (float)h[5] - l;
    o2.z = (float)h[6] - l; o2.w = (float)h[7] - l;
    dst[c * 2] = o1; dst[c * 2 + 1] = o2;
  }
}

// ---------------- fallback single-pass log-softmax (f32 in d_out) ----------------
__global__ __launch_bounds__(512, 1) void logsm_kernel(float* __restrict__ out) {
  int r = blockIdx.x;
  size_t base = (size_t)r * V_;
  int tid = threadIdx.x;
  float4* op = reinterpret_cast<float4*>(out + base);
  float4 v[16];
  float m = -3.4e38f;
#pragma unroll
  for (int k = 0; k < 16; ++k) {
    int c = tid + (k << 9);
    if (c < 8000) {
      v[k] = op[c];
      m = fmaxf(m, fmaxf(fmaxf(v[k].x, v[k].y), fmaxf(v[k].z, v[k].w)));
    }
  }
  __shared__ float red[8];
#pragma unroll
  for (int o = 32; o > 0; o >>= 1) m = fmaxf(m, __shfl_xor(m, o));
  if ((tid & 63) == 0) red[tid >> 6] = m;
  __syncthreads();
  float mm = red[0];
#pragma unroll
  for (int i = 1; i < 8; ++i) mm = fmaxf(mm, red[i]);
  float s = 0.f;
#pragma unroll
  for (int k = 0; k < 16; ++k) {
    int c = tid + (k << 9);
    if (c < 8000)
      s += expf(v[k].x - mm) + expf(v[k].y - mm) + expf(v[k].z - mm) + expf(v[k].w - mm);
  }
#pragma unroll
  for (int o = 32; o > 0; o >>= 1) s += __shfl_xor(s, o);
  __syncthreads();
  if ((tid & 63) == 0) red[tid >> 6] = s;
  __syncthreads();
  s = 0.f;
#pragma unroll
  for (int i = 0; i < 8; ++i) s += red[i];
  float lse = mm + logf(s);
#pragma unroll
  for (int k = 0; k < 16; ++k) {
    int c = tid + (k << 9);
    if (c < 8000) {
      float4 o4;
      o4.x = v[k].x - lse; o4.y = v[k].y - lse;
      o4.z = v[k].z - lse; o4.w = v[k].w - lse;
      op[c] = o4;
    }
  }
}

extern "C" void kernel_launch(void* const* d_in, const int* in_sizes, int n_in,
                              void* d_out, int out_size, void* d_ws, size_t ws_size,
                              hipStream_t stream) {
  const int*   target = (const int*)d_in[0];
  const float* h0     = (const float*)d_in[1];
  const float* c0     = (const float*)d_in[2];
  const float* enc    = (const float*)d_in[3];
  const int*   mask   = (const int*)d_in[4];
  const float* emb    = (const float*)d_in[5];
  const float* W_ih   = (const float*)d_in[6];
  const float* b_ih   = (const float*)d_in[7];
  const float* W_hh   = (const float*)d_in[8];
  const float* b_hh   = (const float*)d_in[9];
  const float* W_attn = (const float*)d_in[10];
  const float* b_attn = (const float*)d_in[11];
  const float* W_cat  = (const float*)d_in[12];
  const float* b_cat  = (const float*)d_in[13];
  const float* W_out  = (const float*)d_in[14];
  const float* b_out  = (const float*)d_in[15];

  char* ws = (char*)d_ws;
  size_t off = 0;
  auto alloc = [&](size_t bytes) {
    void* p = ws + off;
    off = (off + bytes + 255) & ~(size_t)255;
    return p;
  };
  f16*   keys_f   = (f16*)alloc((size_t)SPAD_ * B_ * H_ * 2);
  f16*   Wattn_f  = (f16*)alloc((size_t)H_ * E_ * 2);
  f16*   Wcat_f   = (f16*)alloc((size_t)H_ * (E_ + H_) * 2);
  f16*   Wout_f   = (f16*)alloc((size_t)V_ * H_ * 2);
  f16*   Wperm    = (f16*)alloc((size_t)4 * H_ * H_ * 2);
  f16*   Wihp     = (f16*)alloc((size_t)4 * H_ * EMB_ * 2);
  float* biasperm = (float*)alloc((size_t)4 * H_ * 4);
  f16*   xin_f    = (f16*)alloc((size_t)T_ * B_ * EMB_ * 2);
  float* xpart    = (float*)alloc((size_t)T_ * B_ * 4 * H_ * 4);
  f16*   catin_f  = (f16*)alloc((size_t)T_ * B_ * (E_ + H_) * 2);
  float* attnw    = (float*)alloc((size_t)B_ * S_ * T_ * 4);
  f16*   catbuf_f = (f16*)alloc((size_t)T_ * B_ * H_ * 2);
  f16*   hbuf     = (f16*)alloc((size_t)(T_ + 1) * B_ * H_ * 2);   // 65 slots

  size_t extra = ((size_t)T_ * B_ * V_ * 2 + 255 + (size_t)T_ * B_ * NCB_ * 4 * 2 + 512);
  bool pathA = (off + extra) <= ws_size;
  f16* lbuf = nullptr; float* pm = nullptr; float* psb = nullptr;
  if (pathA) {
    lbuf = (f16*)alloc((size_t)T_ * B_ * V_ * 2);
    pm   = (float*)alloc((size_t)T_ * B_ * NCB_ * 4);
    psb  = (float*)alloc((size_t)T_ * B_ * NCB_ * 4);
  }
  (void)in_sizes; (void)n_in; (void)out_size;

  f16* hseq_f = hbuf + (size_t)B_ * H_;   // slots 1..64 ARE hseq

  prep_kernel<<<(H_ * H_) / 256, 256, 0, stream>>>(b_ih, b_hh, biasperm, W_hh, Wperm,
                                                   W_ih, Wihp, h0, hbuf, W_attn, Wattn_f,
                                                   target, emb, xin_f);
  // xpart (gate-permuted cols): [T*B, 4H] = xin @ Wihp^T + biasperm   (f32 out)
  gemm_bt_kernel<0, false><<<dim3((T_ * B_) / 128, (4 * H_) / 128), 256, 0, stream>>>(
      xin_f, Wihp, biasperm, xpart, T_ * B_, 4 * H_, EMB_);

  // mega: lstm + keys GEMM + W_cat/W_out cvt, all co-resident
  mega_kernel<<<MEGA_BLOCKS, 512, MEGA_LDS, stream>>>(
      xpart, Wperm, c0, hbuf, enc, Wattn_f, b_attn, keys_f,
      W_cat, Wcat_f, W_out, Wout_f);

  scores_mfma_kernel<<<dim3(SPAD_ / 128, B_), 256, 0, stream>>>(keys_f, hseq_f, attnw);
  softmax_kernel<<<dim3(B_, T_), 64, 0, stream>>>(attnw, mask);
  ctx_cat_kernel<<<dim3(B_, 17), 256, 0, stream>>>(attnw, enc, hseq_f, catin_f);

  // cat: [T*B, H] = tanh(catin @ W_cat^T + b_cat)   (f16 out)
  gemm_bt_kernel<1, true><<<dim3((T_ * B_) / 128, H_ / 128), 256, 0, stream>>>(
      catin_f, Wcat_f, b_cat, catbuf_f, T_ * B_, H_, E_ + H_);

  if (pathA) {
    gemm_out256_kernel<<<dim3((T_ * B_) / 256, V_ / 128), 512, 0, stream>>>(
        catbuf_f, Wout_f, b_out, lbuf, pm, psb);
    final_out_kernel<<<T_ * B_, 256, 0, stream>>>(lbuf, pm, psb, (float*)d_out);
  } else {
    gemm_bt_kernel<2, false><<<dim3((T_ * B_) / 128, V_ / 128), 256, 0, stream>>>(
        catbuf_f, Wout_f, b_out, (float*)d_out, T_ * B_, V_, H_);
    logsm_kernel<<<B_ * T_, 512, 0, stream>>>((float*)d_out);
  }
}